// Round 14
// baseline (148.529 us; speedup 1.0000x reference)
//
#include <hip/hip_runtime.h>
#include <stdint.h>

#define TLEN  4096
#define BATCH 128
#define NG    6      // groups: 2 joint-pairs (32 co, 24-ci union) per block
#define TT    256    // output t per tile
#define NIT   4      // tiles per block (persistent, double-buffered LDS)
#define ROWS  272    // 256 + 16 halo; rows 270..271 zeroed (tap-15 pad)
#define NWG   (TLEN / (TT * NIT) * NG * BATCH)   // 3072 blocks, 1D grid

typedef short short8 __attribute__((ext_vector_type(8)));
typedef float f32x4 __attribute__((ext_vector_type(4)));
typedef unsigned int uint;

__device__ __forceinline__ unsigned short f2bf(float f) {
    uint u = __float_as_uint(f);
    u += 0x7fffu + ((u >> 16) & 1u);
    return (unsigned short)(u >> 16);
}
__device__ __forceinline__ int reflect(int tg) {
    return tg < 0 ? -tg : (tg >= TLEN ? 2 * TLEN - 2 - tg : tg);
}

// Masked bf16 weight fragments: wf[p][co_l(16)][kk(256)], kk = k*16 + ci_l.
__global__ __launch_bounds__(256) void prep_weights_kernel(
    const float* __restrict__ w, unsigned short* __restrict__ wf)
{
    int e = blockIdx.x * 256 + threadIdx.x;   // 12*16*256 = 49152
    int kk   = e & 255;
    int co_l = (e >> 8) & 15;
    int p    = e >> 12;
    int k    = kk >> 4;
    int ci_l = kk & 15;
    int jo = 2 * p + (co_l >> 3);
    int jn = 2 * p - 1 + (ci_l >> 2);
    int ci_g = 8 * p - 4 + ci_l;
    float v = 0.0f;
    if (k < 15 && jn >= 0 && jn < 24 && jn >= jo - 1 && jn <= jo + 1)
        v = w[((size_t)(16 * p + co_l) * 96 + ci_g) * 15 + k];
    wf[e] = f2bf(v);
}

__global__ __launch_bounds__(256, 3) void skel_conv_kernel(
    const float* __restrict__ x, const unsigned short* __restrict__ wf,
    const float* __restrict__ bias, float* __restrict__ out)
{
    // double-buffered x tile [row][ci_union 24] bf16, 48 B rows
    __shared__ __align__(16) unsigned short xlds[2][ROWS * 24];

    // ---- XCD-aware swizzle (T1): dispatch id -> XCD = id % 8 (round-robin).
    // swz gives each XCD a contiguous 384-block chunk; chunk-local order is
    // g-fastest so same-XCD-concurrent blocks share (b, t-range) with
    // overlapping 24-ci windows -> overlap + halo re-reads become L2 hits.
    const int id  = blockIdx.x;
    const int swz = (id & 7) * (NWG / 8) + (id >> 3);
    const int b   = swz / (NG * 4);                 // 24 blocks per batch
    const int rem = swz - b * (NG * 4);
    const int tx  = rem / NG;
    const int g   = rem - tx * NG;
    const int tb0 = tx * (TT * NIT);

    const int tid  = threadIdx.x;
    const int lane = tid & 63;
    const int wave = tid >> 6;
    const int q     = wave & 1;     // pair within group
    const int thalf = wave >> 1;    // 128-t half
    const int p     = 2 * g + q;    // global pair
    const int col  = lane & 15;     // W col (co) / X row (t) / D col (co)
    const int hi2  = lane >> 4;     // K sub-block selector

    const int ciBase = 16 * g - 4;
    const float* xb = x + (size_t)b * 96 * TLEN;

    // ---- W fragments (once per block), PINNED in VGPRs ----
    short8 wfrag[8];
    {
        const unsigned short* wp = wf + (size_t)(p * 16 + col) * 256 + hi2 * 8;
        #pragma unroll
        for (int s = 0; s < 8; ++s)
            wfrag[s] = *reinterpret_cast<const short8*>(wp + s * 32);
    }
    #pragma unroll
    for (int s = 0; s < 8; ++s)
        asm volatile("" : "+v"(wfrag[s]));

    // ---- bias: one scalar per lane (co = lane&15), folded into acc init ----
    const float bv = bias[16 * p + col];

    // halo work: rows 256..271, ci 0..23, coalesced 16-lane strips
    const int hr  = 256 + (tid & 15);
    const int hc0 = tid >> 4;          // 0..15
    const int hc1 = 16 + (tid >> 4);   // valid (<24) iff tid < 128

    // single staging register bank (R6 structure)
    float v[24], hv0, hv1;

    auto STAGE_ISSUE = [&](int tt0) {
        int src = reflect(tt0 - 7 + tid);           // main row = tid (<270)
        const float* xs = xb + src;
        #pragma unroll
        for (int c = 0; c < 24; ++c) {
            int cg = ciBase + c;
            v[c] = ((unsigned)cg < 96u) ? xs[(size_t)cg * TLEN] : 0.f;
        }
        int hsrc = reflect(tt0 - 7 + hr);
        int cg0 = ciBase + hc0;
        hv0 = (hr < 270 && (unsigned)cg0 < 96u) ? xb[(size_t)cg0 * TLEN + hsrc] : 0.f;
        int cg1 = ciBase + hc1;
        hv1 = (tid < 128 && hr < 270 && (unsigned)cg1 < 96u) ? xb[(size_t)cg1 * TLEN + hsrc] : 0.f;
    };

    auto STAGE_WRITE = [&](unsigned short* buf) {
        uint vals[12];
        #pragma unroll
        for (int qq = 0; qq < 12; ++qq)
            vals[qq] = (uint)f2bf(v[2 * qq]) | ((uint)f2bf(v[2 * qq + 1]) << 16);
        *reinterpret_cast<uint4*>(&buf[tid * 24 + 0])  = make_uint4(vals[0], vals[1], vals[2],  vals[3]);
        *reinterpret_cast<uint4*>(&buf[tid * 24 + 8])  = make_uint4(vals[4], vals[5], vals[6],  vals[7]);
        *reinterpret_cast<uint4*>(&buf[tid * 24 + 16]) = make_uint4(vals[8], vals[9], vals[10], vals[11]);
        buf[hr * 24 + hc0] = f2bf(hv0);
        if (tid < 128) buf[hr * 24 + hc1] = f2bf(hv1);
    };

    // prologue: fill buffer 0
    STAGE_ISSUE(tb0);
    STAGE_WRITE(xlds[0]);
    __syncthreads();

    const int ci0   = 8 * q + 8 * (hi2 & 1);  // pair q's ci window half
    const int kb    = hi2 >> 1;               // k-tap low bit
    const int rbase = thalf * 128 + col + kb;

    #pragma unroll
    for (int it = 0; it < NIT; ++it) {
        const unsigned short* buf = xlds[it & 1];

        // issue next tile's global loads; sched_barrier pins them above the
        // MFMA phase (R5 failure: hipcc re-sank them, serializing phases).
        if (it + 1 < NIT) STAGE_ISSUE(tb0 + (it + 1) * TT);
        __builtin_amdgcn_sched_barrier(0);

        f32x4 acc[8];
        #pragma unroll
        for (int nf = 0; nf < 8; ++nf)
            acc[nf] = (f32x4){bv, bv, bv, bv};

        // X as the A operand, W as the B operand: D row = t, col = co.
        // A/B 16x16x32 register layouts are symmetric (lane&15 = M for A,
        // N for B; k = 8*(lane>>4)+j for both), so the fragments and LDS
        // read pattern are byte-identical to the old order — only D flips,
        // giving each lane 4 CONSECUTIVE t per nf -> dwordx4 stores.
        #pragma unroll
        for (int s = 0; s < 8; ++s) {
            const unsigned short* bp = &buf[(rbase + 2 * s) * 24 + ci0];
            #pragma unroll
            for (int nf = 0; nf < 8; ++nf) {
                short8 xfrag = *reinterpret_cast<const short8*>(bp + nf * (16 * 24));
                acc[nf] = __builtin_amdgcn_mfma_f32_16x16x32_bf16(xfrag, wfrag[s], acc[nf], 0, 0, 0);
            }
        }

        // convert + LDS-write the prefetched tile (loads returned under MFMA)
        if (it + 1 < NIT) STAGE_WRITE(xlds[(it + 1) & 1]);
        __syncthreads();

        // stores after the barrier: one float4 per nf (was 4 scalar dwords)
        float* ob = out + ((size_t)b * 192 + 16 * p + col) * TLEN
                  + tb0 + it * TT + thalf * 128 + 4 * hi2;
        #pragma unroll
        for (int nf = 0; nf < 8; ++nf)
            *reinterpret_cast<f32x4*>(&ob[nf * 16]) = acc[nf];
    }
}

extern "C" void kernel_launch(void* const* d_in, const int* in_sizes, int n_in,
                              void* d_out, int out_size, void* d_ws, size_t ws_size,
                              hipStream_t stream) {
    const float* x    = (const float*)d_in[0];
    const float* w    = (const float*)d_in[1];
    const float* bias = (const float*)d_in[2];
    float* out        = (float*)d_out;
    unsigned short* wf = (unsigned short*)d_ws;   // 98304 B

    prep_weights_kernel<<<dim3(192), dim3(256), 0, stream>>>(w, wf);
    skel_conv_kernel<<<dim3(NWG), dim3(256), 0, stream>>>(x, wf, bias, out);
}

// Round 15
// 143.356 us; speedup vs baseline: 1.0361x; 1.0361x over previous
//
#include <hip/hip_runtime.h>
#include <stdint.h>

#define TLEN  4096
#define BATCH 128
#define NG    6      // groups: 2 joint-pairs (32 co, 24-ci union) per block
#define TT    256    // output t per tile
#define NIT   8      // tiles per block: grid 1536 = 2 rounds of 3 blocks/CU
#define ROWS  272    // 256 + 16 halo; rows 270..271 zeroed (tap-15 pad)
#define NWG   (TLEN / (TT * NIT) * NG * BATCH)   // 1536 blocks, 1D grid

typedef short short8 __attribute__((ext_vector_type(8)));
typedef float f32x4 __attribute__((ext_vector_type(4)));
typedef unsigned int uint;

__device__ __forceinline__ unsigned short f2bf(float f) {
    uint u = __float_as_uint(f);
    u += 0x7fffu + ((u >> 16) & 1u);
    return (unsigned short)(u >> 16);
}
__device__ __forceinline__ int reflect(int tg) {
    return tg < 0 ? -tg : (tg >= TLEN ? 2 * TLEN - 2 - tg : tg);
}

// Masked bf16 weight fragments: wf[p][co_l(16)][kk(256)], kk = k*16 + ci_l.
__global__ __launch_bounds__(256) void prep_weights_kernel(
    const float* __restrict__ w, unsigned short* __restrict__ wf)
{
    int e = blockIdx.x * 256 + threadIdx.x;   // 12*16*256 = 49152
    int kk   = e & 255;
    int co_l = (e >> 8) & 15;
    int p    = e >> 12;
    int k    = kk >> 4;
    int ci_l = kk & 15;
    int jo = 2 * p + (co_l >> 3);
    int jn = 2 * p - 1 + (ci_l >> 2);
    int ci_g = 8 * p - 4 + ci_l;
    float v = 0.0f;
    if (k < 15 && jn >= 0 && jn < 24 && jn >= jo - 1 && jn <= jo + 1)
        v = w[((size_t)(16 * p + co_l) * 96 + ci_g) * 15 + k];
    wf[e] = f2bf(v);
}

__global__ __launch_bounds__(256, 3) void skel_conv_kernel(
    const float* __restrict__ x, const unsigned short* __restrict__ wf,
    const float* __restrict__ bias, float* __restrict__ out)
{
    // double-buffered x tile [row][ci_union 24] bf16, 48 B rows
    __shared__ __align__(16) unsigned short xlds[2][ROWS * 24];

    // ---- XCD-aware swizzle (T1): dispatch id -> XCD = id % 8 (round-robin).
    // swz gives each XCD a contiguous 192-block chunk; chunk-local order is
    // g-fastest so same-XCD-concurrent blocks share (b, t-range) with
    // overlapping 24-ci windows -> overlap + halo re-reads become L2 hits.
    const int id  = blockIdx.x;
    const int swz = (id & 7) * (NWG / 8) + (id >> 3);
    const int b   = swz / (NG * 2);                 // 12 blocks per batch
    const int rem = swz - b * (NG * 2);
    const int tx  = rem / NG;
    const int g   = rem - tx * NG;
    const int tb0 = tx * (TT * NIT);

    const int tid  = threadIdx.x;
    const int lane = tid & 63;
    const int wave = tid >> 6;
    const int q     = wave & 1;     // pair within group
    const int thalf = wave >> 1;    // 128-t half
    const int p     = 2 * g + q;    // global pair
    const int col  = lane & 15;     // A row (co) / B,D col (t)
    const int hi2  = lane >> 4;     // K sub-block selector

    const int ciBase = 16 * g - 4;
    const float* xb = x + (size_t)b * 96 * TLEN;

    // ---- A fragments (once per block), PINNED in VGPRs ----
    short8 afrag[8];
    {
        const unsigned short* wp = wf + (size_t)(p * 16 + col) * 256 + hi2 * 8;
        #pragma unroll
        for (int s = 0; s < 8; ++s)
            afrag[s] = *reinterpret_cast<const short8*>(wp + s * 32);
    }
    #pragma unroll
    for (int s = 0; s < 8; ++s)
        asm volatile("" : "+v"(afrag[s]));

    // ---- bias (folded into acc init) ----
    const int colb = 4 * hi2;
    float bv[4];
    #pragma unroll
    for (int r = 0; r < 4; ++r) bv[r] = bias[16 * p + colb + r];

    // halo work: rows 256..271, ci 0..23, coalesced 16-lane strips
    const int hr  = 256 + (tid & 15);
    const int hc0 = tid >> 4;          // 0..15
    const int hc1 = 16 + (tid >> 4);   // valid (<24) iff tid < 128

    // single staging register bank (R6 structure)
    float v[24], hv0, hv1;

    auto STAGE_ISSUE = [&](int tt0) {
        int src = reflect(tt0 - 7 + tid);           // main row = tid (<270)
        const float* xs = xb + src;
        #pragma unroll
        for (int c = 0; c < 24; ++c) {
            int cg = ciBase + c;
            v[c] = ((unsigned)cg < 96u) ? xs[(size_t)cg * TLEN] : 0.f;
        }
        int hsrc = reflect(tt0 - 7 + hr);
        int cg0 = ciBase + hc0;
        hv0 = (hr < 270 && (unsigned)cg0 < 96u) ? xb[(size_t)cg0 * TLEN + hsrc] : 0.f;
        int cg1 = ciBase + hc1;
        hv1 = (tid < 128 && hr < 270 && (unsigned)cg1 < 96u) ? xb[(size_t)cg1 * TLEN + hsrc] : 0.f;
    };

    auto STAGE_WRITE = [&](unsigned short* buf) {
        uint vals[12];
        #pragma unroll
        for (int qq = 0; qq < 12; ++qq)
            vals[qq] = (uint)f2bf(v[2 * qq]) | ((uint)f2bf(v[2 * qq + 1]) << 16);
        *reinterpret_cast<uint4*>(&buf[tid * 24 + 0])  = make_uint4(vals[0], vals[1], vals[2],  vals[3]);
        *reinterpret_cast<uint4*>(&buf[tid * 24 + 8])  = make_uint4(vals[4], vals[5], vals[6],  vals[7]);
        *reinterpret_cast<uint4*>(&buf[tid * 24 + 16]) = make_uint4(vals[8], vals[9], vals[10], vals[11]);
        buf[hr * 24 + hc0] = f2bf(hv0);
        if (tid < 128) buf[hr * 24 + hc1] = f2bf(hv1);
    };

    // prologue: fill buffer 0 (amortized over 8 tiles)
    STAGE_ISSUE(tb0);
    STAGE_WRITE(xlds[0]);
    __syncthreads();

    const int ci0   = 8 * q + 8 * (hi2 & 1);  // pair q's ci window half
    const int kb    = hi2 >> 1;               // k-tap low bit
    const int rbase = thalf * 128 + col + kb;

    #pragma unroll
    for (int it = 0; it < NIT; ++it) {
        const unsigned short* buf = xlds[it & 1];

        // issue next tile's global loads; sched_barrier pins them above the
        // MFMA phase (R5 failure: hipcc re-sank them, serializing phases).
        if (it + 1 < NIT) STAGE_ISSUE(tb0 + (it + 1) * TT);
        __builtin_amdgcn_sched_barrier(0);

        f32x4 acc[8];
        #pragma unroll
        for (int nf = 0; nf < 8; ++nf)
            acc[nf] = (f32x4){bv[0], bv[1], bv[2], bv[3]};

        #pragma unroll
        for (int s = 0; s < 8; ++s) {
            const unsigned short* bp = &buf[(rbase + 2 * s) * 24 + ci0];
            #pragma unroll
            for (int nf = 0; nf < 8; ++nf) {
                short8 bfrag = *reinterpret_cast<const short8*>(bp + nf * (16 * 24));
                acc[nf] = __builtin_amdgcn_mfma_f32_16x16x32_bf16(afrag[s], bfrag, acc[nf], 0, 0, 0);
            }
        }

        // convert + LDS-write the prefetched tile (loads returned under MFMA)
        if (it + 1 < NIT) STAGE_WRITE(xlds[(it + 1) & 1]);
        __syncthreads();

        // stores after the barrier: drain overlaps next tile's MFMA phase
        float* ob = out + ((size_t)b * 192 + 16 * p + colb) * TLEN
                  + tb0 + it * TT + thalf * 128 + col;
        #pragma unroll
        for (int nf = 0; nf < 8; ++nf) {
            #pragma unroll
            for (int r = 0; r < 4; ++r)
                ob[(size_t)r * TLEN + nf * 16] = acc[nf][r];
        }
    }
}

extern "C" void kernel_launch(void* const* d_in, const int* in_sizes, int n_in,
                              void* d_out, int out_size, void* d_ws, size_t ws_size,
                              hipStream_t stream) {
    const float* x    = (const float*)d_in[0];
    const float* w    = (const float*)d_in[1];
    const float* bias = (const float*)d_in[2];
    float* out        = (float*)d_out;
    unsigned short* wf = (unsigned short*)d_ws;   // 98304 B

    prep_weights_kernel<<<dim3(192), dim3(256), 0, stream>>>(w, wf);
    skel_conv_kernel<<<dim3(NWG), dim3(256), 0, stream>>>(x, wf, bias, out);
}

// Round 16
// 131.964 us; speedup vs baseline: 1.1255x; 1.0863x over previous
//
#include <hip/hip_runtime.h>
#include <stdint.h>

#define TLEN  4096
#define BATCH 128
#define NG    6      // groups: 2 joint-pairs (32 co, 24-ci union) per block
#define TT    256    // output t per tile
#define NIT   4      // tiles per block (persistent, double-buffered LDS)
#define ROWS  272    // 256 + 16 halo; rows 270..271 zeroed (tap-15 pad)
#define NWG   (TLEN / (TT * NIT) * NG * BATCH)   // 3072 blocks, 1D grid

typedef short short8 __attribute__((ext_vector_type(8)));
typedef float f32x4 __attribute__((ext_vector_type(4)));
typedef unsigned int uint;

__device__ __forceinline__ unsigned short f2bf(float f) {
    uint u = __float_as_uint(f);
    u += 0x7fffu + ((u >> 16) & 1u);
    return (unsigned short)(u >> 16);
}
__device__ __forceinline__ int reflect(int tg) {
    return tg < 0 ? -tg : (tg >= TLEN ? 2 * TLEN - 2 - tg : tg);
}

// Masked bf16 weight fragments: wf[p][co_l(16)][kk(256)], kk = k*16 + ci_l.
__global__ __launch_bounds__(256) void prep_weights_kernel(
    const float* __restrict__ w, unsigned short* __restrict__ wf)
{
    int e = blockIdx.x * 256 + threadIdx.x;   // 12*16*256 = 49152
    int kk   = e & 255;
    int co_l = (e >> 8) & 15;
    int p    = e >> 12;
    int k    = kk >> 4;
    int ci_l = kk & 15;
    int jo = 2 * p + (co_l >> 3);
    int jn = 2 * p - 1 + (ci_l >> 2);
    int ci_g = 8 * p - 4 + ci_l;
    float v = 0.0f;
    if (k < 15 && jn >= 0 && jn < 24 && jn >= jo - 1 && jn <= jo + 1)
        v = w[((size_t)(16 * p + co_l) * 96 + ci_g) * 15 + k];
    wf[e] = f2bf(v);
}

__global__ __launch_bounds__(256, 3) void skel_conv_kernel(
    const float* __restrict__ x, const unsigned short* __restrict__ wf,
    const float* __restrict__ bias, float* __restrict__ out)
{
    // double-buffered x tile [row][ci_union 24] bf16, 48 B rows
    __shared__ __align__(16) unsigned short xlds[2][ROWS * 24];

    // ---- XCD-aware swizzle (T1): dispatch id -> XCD = id % 8 (round-robin).
    // swz gives each XCD a contiguous 384-block chunk; chunk-local order is
    // g-fastest so same-XCD-concurrent blocks share (b, t-range) with
    // overlapping 24-ci windows -> overlap + halo re-reads become L2 hits.
    const int id  = blockIdx.x;
    const int swz = (id & 7) * (NWG / 8) + (id >> 3);
    const int b   = swz / (NG * 4);                 // 24 blocks per batch
    const int rem = swz - b * (NG * 4);
    const int tx  = rem / NG;
    const int g   = rem - tx * NG;
    const int tb0 = tx * (TT * NIT);

    const int tid  = threadIdx.x;
    const int lane = tid & 63;
    const int wave = tid >> 6;
    const int q     = wave & 1;     // pair within group
    const int thalf = wave >> 1;    // 128-t half
    const int p     = 2 * g + q;    // global pair
    const int col  = lane & 15;     // A row (co) / B,D col (t)
    const int hi2  = lane >> 4;     // K sub-block selector

    const int ciBase = 16 * g - 4;
    const float* xb = x + (size_t)b * 96 * TLEN;

    // ---- A fragments (once per block), PINNED in VGPRs ----
    short8 afrag[8];
    {
        const unsigned short* wp = wf + (size_t)(p * 16 + col) * 256 + hi2 * 8;
        #pragma unroll
        for (int s = 0; s < 8; ++s)
            afrag[s] = *reinterpret_cast<const short8*>(wp + s * 32);
    }
    #pragma unroll
    for (int s = 0; s < 8; ++s)
        asm volatile("" : "+v"(afrag[s]));

    // ---- bias (folded into acc init) ----
    const int colb = 4 * hi2;
    float bv[4];
    #pragma unroll
    for (int r = 0; r < 4; ++r) bv[r] = bias[16 * p + colb + r];

    // halo work: rows 256..271, ci 0..23, coalesced 16-lane strips
    const int hr  = 256 + (tid & 15);
    const int hc0 = tid >> 4;          // 0..15
    const int hc1 = 16 + (tid >> 4);   // valid (<24) iff tid < 128

    // single staging register bank (R6 structure)
    float v[24], hv0, hv1;

    auto STAGE_ISSUE = [&](int tt0) {
        int src = reflect(tt0 - 7 + tid);           // main row = tid (<270)
        const float* xs = xb + src;
        #pragma unroll
        for (int c = 0; c < 24; ++c) {
            int cg = ciBase + c;
            v[c] = ((unsigned)cg < 96u) ? xs[(size_t)cg * TLEN] : 0.f;
        }
        int hsrc = reflect(tt0 - 7 + hr);
        int cg0 = ciBase + hc0;
        hv0 = (hr < 270 && (unsigned)cg0 < 96u) ? xb[(size_t)cg0 * TLEN + hsrc] : 0.f;
        int cg1 = ciBase + hc1;
        hv1 = (tid < 128 && hr < 270 && (unsigned)cg1 < 96u) ? xb[(size_t)cg1 * TLEN + hsrc] : 0.f;
    };

    auto STAGE_WRITE = [&](unsigned short* buf) {
        uint vals[12];
        #pragma unroll
        for (int qq = 0; qq < 12; ++qq)
            vals[qq] = (uint)f2bf(v[2 * qq]) | ((uint)f2bf(v[2 * qq + 1]) << 16);
        *reinterpret_cast<uint4*>(&buf[tid * 24 + 0])  = make_uint4(vals[0], vals[1], vals[2],  vals[3]);
        *reinterpret_cast<uint4*>(&buf[tid * 24 + 8])  = make_uint4(vals[4], vals[5], vals[6],  vals[7]);
        *reinterpret_cast<uint4*>(&buf[tid * 24 + 16]) = make_uint4(vals[8], vals[9], vals[10], vals[11]);
        buf[hr * 24 + hc0] = f2bf(hv0);
        if (tid < 128) buf[hr * 24 + hc1] = f2bf(hv1);
    };

    // prologue: fill buffer 0
    STAGE_ISSUE(tb0);
    STAGE_WRITE(xlds[0]);
    __syncthreads();

    const int ci0   = 8 * q + 8 * (hi2 & 1);  // pair q's ci window half
    const int kb    = hi2 >> 1;               // k-tap low bit
    const int rbase = thalf * 128 + col + kb;

    #pragma unroll
    for (int it = 0; it < NIT; ++it) {
        const unsigned short* buf = xlds[it & 1];

        // issue next tile's global loads; sched_barrier pins them above the
        // MFMA phase (R5 failure: hipcc re-sank them, serializing phases).
        if (it + 1 < NIT) STAGE_ISSUE(tb0 + (it + 1) * TT);
        __builtin_amdgcn_sched_barrier(0);

        f32x4 acc[8];
        #pragma unroll
        for (int nf = 0; nf < 8; ++nf)
            acc[nf] = (f32x4){bv[0], bv[1], bv[2], bv[3]};

        #pragma unroll
        for (int s = 0; s < 8; ++s) {
            const unsigned short* bp = &buf[(rbase + 2 * s) * 24 + ci0];
            #pragma unroll
            for (int nf = 0; nf < 8; ++nf) {
                short8 bfrag = *reinterpret_cast<const short8*>(bp + nf * (16 * 24));
                acc[nf] = __builtin_amdgcn_mfma_f32_16x16x32_bf16(afrag[s], bfrag, acc[nf], 0, 0, 0);
            }
        }

        // convert + LDS-write the prefetched tile (loads returned under MFMA)
        if (it + 1 < NIT) STAGE_WRITE(xlds[(it + 1) & 1]);
        __syncthreads();

        // non-temporal stores: out is write-once/never-read — bypass L2/L3
        // so x panels (whose L2 residency the XCD swizzle just proved worth
        // ~7 us) aren't evicted by 403 MB of dead output lines.
        float* ob = out + ((size_t)b * 192 + 16 * p + colb) * TLEN
                  + tb0 + it * TT + thalf * 128 + col;
        #pragma unroll
        for (int nf = 0; nf < 8; ++nf) {
            #pragma unroll
            for (int r = 0; r < 4; ++r)
                __builtin_nontemporal_store(acc[nf][r], &ob[(size_t)r * TLEN + nf * 16]);
        }
    }
}

extern "C" void kernel_launch(void* const* d_in, const int* in_sizes, int n_in,
                              void* d_out, int out_size, void* d_ws, size_t ws_size,
                              hipStream_t stream) {
    const float* x    = (const float*)d_in[0];
    const float* w    = (const float*)d_in[1];
    const float* bias = (const float*)d_in[2];
    float* out        = (float*)d_out;
    unsigned short* wf = (unsigned short*)d_ws;   // 98304 B

    prep_weights_kernel<<<dim3(192), dim3(256), 0, stream>>>(w, wf);
    skel_conv_kernel<<<dim3(NWG), dim3(256), 0, stream>>>(x, wf, bias, out);
}